// Round 1
// 498.435 us; speedup vs baseline: 1.0390x; 1.0390x over previous
//
#include <hip/hip_runtime.h>

// DeepseekV3MoE on MI355X (gfx950), bf16-MFMA, round 5.
// Round-5 change: big GEMMs moved to a counted-vmcnt software pipeline:
//   128x256 tile, 512 threads (8 waves 2x4, 64x64 per wave), BK=32,
//   triple-buffered LDS (3 x 24KB = 72KB), s_waitcnt vmcnt(3) + raw s_barrier
//   (loads for step t+1 stay in flight across the barrier; never drain in loop),
//   setprio(1) around the 16-MFMA cluster. 2 blocks/CU (144KB LDS, <=128 VGPR).
// Also merged: silu(gur)+silu(gus) into one launch; wg+wu and sg+su tcasts
// into one launch each. Gate/scan/assign/combine and fallback path unchanged.

typedef unsigned short u16;
typedef unsigned int   u32;
typedef __bf16 bf16x8 __attribute__((ext_vector_type(8)));
typedef float  f32x4  __attribute__((ext_vector_type(4)));

#define T_TOK 2048
#define HDIM  2048
#define IDIM  1024
#define NEXP  8
#define ISDIM 2048
#define MAXROWS 5120   // 4096 + 8*127 -> 5112, rounded up to 128-multiple

__device__ __forceinline__ u16 f2bf(float f) {
  u32 x = __float_as_uint(f);
  return (u16)((x + 0x7FFFu + ((x >> 16) & 1u)) >> 16);
}
__device__ __forceinline__ float bf2f(u16 v) { return __uint_as_float(((u32)v) << 16); }

#define GLL(g, l)                                                              \
  __builtin_amdgcn_global_load_lds(                                            \
      (const __attribute__((address_space(1))) void*)(g),                      \
      (__attribute__((address_space(3))) void*)(l), 16, 0, 0)

// ---------------- init: perm=-1, meta=0, zrow=0 ----------------
__global__ void init_kernel(int* __restrict__ perm, int* __restrict__ meta,
                            int* __restrict__ zrow) {
  int idx = blockIdx.x * 256 + threadIdx.x;
  if (idx < 8192) perm[idx] = -1;
  if (idx < 16) meta[idx] = 0;
  if (idx < 1024) zrow[idx] = 0;
}

// ---------------- gate: logits->top2->renorm; fused x cast + out zero ----------------
__global__ __launch_bounds__(256) void gate_kernel(
    const float* __restrict__ x, const float* __restrict__ gw,
    u16* __restrict__ xb, float* __restrict__ outz,
    float* __restrict__ topw, int* __restrict__ topi, int* __restrict__ meta) {
  const int t = blockIdx.x, tid = threadIdx.x;
  const long o = (long)t * HDIM + tid * 8;
  float4 a = *(const float4*)(x + o);
  float4 b = *(const float4*)(x + o + 4);
  float4 z = {0.f, 0.f, 0.f, 0.f};
  *(float4*)(outz + o) = z;
  *(float4*)(outz + o + 4) = z;
  uint4 w;
  w.x = (u32)f2bf(a.x) | ((u32)f2bf(a.y) << 16);
  w.y = (u32)f2bf(a.z) | ((u32)f2bf(a.w) << 16);
  w.z = (u32)f2bf(b.x) | ((u32)f2bf(b.y) << 16);
  w.w = (u32)f2bf(b.z) | ((u32)f2bf(b.w) << 16);
  *(uint4*)(xb + o) = w;
  float acc[NEXP];
#pragma unroll
  for (int e = 0; e < NEXP; e++) {
    const float* gr = gw + e * HDIM + tid * 8;
    float4 wa = *(const float4*)gr;
    float4 wb = *(const float4*)(gr + 4);
    acc[e] = a.x * wa.x + a.y * wa.y + a.z * wa.z + a.w * wa.w +
             b.x * wb.x + b.y * wb.y + b.z * wb.z + b.w * wb.w;
  }
#pragma unroll
  for (int off = 32; off; off >>= 1)
#pragma unroll
    for (int e = 0; e < NEXP; e++) acc[e] += __shfl_down(acc[e], off, 64);
  __shared__ float red[4][NEXP];
  if ((tid & 63) == 0) {
#pragma unroll
    for (int e = 0; e < NEXP; e++) red[tid >> 6][e] = acc[e];
  }
  __syncthreads();
  if (tid == 0) {
    float s[NEXP];
#pragma unroll
    for (int e = 0; e < NEXP; e++) s[e] = red[0][e] + red[1][e] + red[2][e] + red[3][e];
    int i0 = 0;
#pragma unroll
    for (int e = 1; e < NEXP; e++)
      if (s[e] > s[i0]) i0 = e;
    int i1 = -1;
#pragma unroll
    for (int e = 0; e < NEXP; e++) {
      if (e == i0) continue;
      if (i1 < 0 || s[e] > s[i1]) i1 = e;
    }
    float w0 = 1.f / (1.f + __expf(s[i1] - s[i0]));  // softmax->top2->renorm
    topw[t * 2 + 0] = w0;
    topw[t * 2 + 1] = 1.f - w0;
    topi[t * 2 + 0] = i0;
    topi[t * 2 + 1] = i1;
    atomicAdd(meta + i0, 1);
    atomicAdd(meta + i1, 1);
  }
}

// ---------------- scan: padded exclusive offsets meta[16..24] ----------------
__global__ void scan_kernel(int* __restrict__ meta) {
  if (threadIdx.x == 0 && blockIdx.x == 0) {
    int o = 0;
    meta[16] = 0;
#pragma unroll
    for (int e = 0; e < NEXP; e++) {
      o += (meta[e] + 127) & ~127;
      meta[17 + e] = o;
    }
  }
}

// ---------------- assign: perm[row]=t*2+slot, tokrow[t*2+slot]=row ----------------
__global__ void assign_kernel(const int* __restrict__ topi, int* __restrict__ meta,
                              int* __restrict__ perm, int* __restrict__ tokrow) {
  int idx = blockIdx.x * 256 + threadIdx.x;  // < 4096
  int e = topi[idx];
  int pos = atomicAdd(meta + 8 + e, 1);
  int row = meta[16 + e] + pos;
  perm[row] = idx;
  tokrow[idx] = row;
}

// ---------------- transpose-cast tile core ----------------
__device__ __forceinline__ void tcast_tile(const float* __restrict__ in,
                                           u16* __restrict__ out, int R, int C) {
  __shared__ float tile[64 * 65];
  int r0 = blockIdx.y * 64, c0 = blockIdx.x * 64;
  int t = threadIdx.x;
  int i = t >> 4, j4 = t & 15;
#pragma unroll
  for (int ii = 0; ii < 4; ii++) {
    int r = i + ii * 16;
    float4 v = *(const float4*)(in + (long)(r0 + r) * C + c0 + j4 * 4);
    tile[r * 65 + j4 * 4 + 0] = v.x;
    tile[r * 65 + j4 * 4 + 1] = v.y;
    tile[r * 65 + j4 * 4 + 2] = v.z;
    tile[r * 65 + j4 * 4 + 3] = v.w;
  }
  __syncthreads();
  int cc = t >> 3, rr = (t & 7) * 8;
#pragma unroll
  for (int pp = 0; pp < 2; pp++) {
    int c = cc + pp * 32;
    u16 e[8];
#pragma unroll
    for (int u = 0; u < 8; u++) e[u] = f2bf(tile[(rr + u) * 65 + c]);
    uint4 w;
    w.x = (u32)e[0] | ((u32)e[1] << 16);
    w.y = (u32)e[2] | ((u32)e[3] << 16);
    w.z = (u32)e[4] | ((u32)e[5] << 16);
    w.w = (u32)e[6] | ((u32)e[7] << 16);
    *(uint4*)(out + (long)(c0 + c) * R + r0 + rr) = w;
  }
}

// ---------------- transpose-cast: fp32 [R][C] -> bf16 [C][R], z-strided ----------------
__global__ __launch_bounds__(256) void tcast_kernel(const float* __restrict__ in,
                                                    u16* __restrict__ out, int R, int C,
                                                    long inz, long outz) {
  tcast_tile(in + (long)blockIdx.z * inz, out + (long)blockIdx.z * outz, R, C);
}

// ---- merged two-source tcast (A for z<zsplit, B after at +boff) ----
__global__ __launch_bounds__(256) void tcast2_kernel(
    const float* __restrict__ inA, const float* __restrict__ inB,
    u16* __restrict__ out, int R, int C, long inz, long outz, long boff, int zsplit) {
  int z = blockIdx.z;
  const float* in;
  u16* o;
  if (z < zsplit) {
    in = inA + (long)z * inz;
    o = out + (long)z * outz;
  } else {
    int e = z - zsplit;
    in = inB + (long)e * inz;
    o = out + (long)e * outz + boff;
  }
  tcast_tile(in, o, R, C);
}

// ---------------- silu-mul in place ----------------
template <int HALF8>  // half-width / 8
__device__ __forceinline__ void silu_do(u16* __restrict__ buf, long i) {
  long r = i / HALF8, c = i % HALF8;
  u16* g = buf + r * (long)HALF8 * 16 + c * 8;
  uint4 gv = *(const uint4*)g;
  uint4 uv = *(const uint4*)(g + HALF8 * 8);
  const u32* gp = &gv.x;
  const u32* up = &uv.x;
  uint4 w;
  u32* wp = &w.x;
#pragma unroll
  for (int j = 0; j < 4; j++) {
    float g0 = bf2f((u16)(gp[j] & 0xFFFF)), g1 = bf2f((u16)(gp[j] >> 16));
    float u0 = bf2f((u16)(up[j] & 0xFFFF)), u1 = bf2f((u16)(up[j] >> 16));
    float r0 = g0 / (1.f + __expf(-g0)) * u0;
    float r1 = g1 / (1.f + __expf(-g1)) * u1;
    wp[j] = (u32)f2bf(r0) | ((u32)f2bf(r1) << 16);
  }
  *(uint4*)g = w;
}

template <int HALF8>
__global__ void silu_kernel(u16* __restrict__ buf) {
  long i = (long)blockIdx.x * 256 + threadIdx.x;
  silu_do<HALF8>(buf, i);
}

// merged: gur (HALF8=128, MAXROWS*IDIM/8 elems) then gus (HALF8=256)
__global__ void silu2_kernel(u16* __restrict__ gur, u16* __restrict__ gus) {
  const long NR = (long)MAXROWS * IDIM / 8;  // 655360, /256 exact
  long i = (long)blockIdx.x * 256 + threadIdx.x;
  if (i < NR)
    silu_do<128>(gur, i);
  else
    silu_do<256>(gus, i - NR);
}

// ================= round-5 pipelined GEMM body =================
// 128(M) x 256(N) tile, BK=32, 512 threads = 8 waves (2x4), 64x64 per wave.
// LDS: 3 buffers of [A 128x32 | B 256x32] bf16 = 3 x 12288 u16 = 72KB.
// Counted pipeline: iter t computes buf[t%3], stages K-step t+2 into buf[(t+2)%3];
// top-of-iter s_waitcnt vmcnt(3) leaves next step's 3 loads in flight.
// Swizzle: chunk slot s at row r holds global chunk s ^ ((r>>1)&3)
// (2-way bank aliasing on ds_read_b128 = free; GLL dests stay linear).
template <int CMODE /*0 bf16, 1 fp32*/, bool PERMA, bool SEGB>
__device__ __forceinline__ void gemm_body2(
    int mt, int nt, u16* lds, const u16* __restrict__ A, long lda,
    const u16* __restrict__ B, long ldbz, int K, u16* __restrict__ Cb,
    float* __restrict__ Cf, long ldc, const int* __restrict__ offp,
    const int* __restrict__ perm, const u16* __restrict__ zrow) {
  const int row0 = mt * 128;
  if constexpr (SEGB) {
    if (row0 >= offp[8]) return;
    int e = 0;
    while (offp[e + 1] <= row0) ++e;
    B += (long)e * ldbz;
  }
  const int tid = threadIdx.x;

  // ---- staging sources (pre-swizzled global chunk; LDS dest linear) ----
  const int ra = tid >> 2, sa = tid & 3;
  const u16* gA;
  if constexpr (PERMA) {
    int p = perm[row0 + ra];
    gA = ((p < 0) ? zrow : A + (long)(p >> 1) * lda) + (sa ^ ((ra >> 1) & 3)) * 8;
  } else {
    gA = A + (long)(row0 + ra) * lda + (sa ^ ((ra >> 1) & 3)) * 8;
  }
  const int rb0 = ra, rb1 = ra + 128;  // B rows (n-index), chunk = sa
  const u16* gB0 = B + (long)(nt * 256 + rb0) * K + (sa ^ ((rb0 >> 1) & 3)) * 8;
  const u16* gB1 = B + (long)(nt * 256 + rb1) * K + (sa ^ ((rb1 >> 1) & 3)) * 8;
  const int dAo = tid * 8;         // A region: [0, 4096) u16
  const int dBo = 4096 + tid * 8;  // B region: [4096, 12288), 2nd chunk at +4096

  // ---- fragment read offsets (element offsets within one buffer) ----
  const int lane = tid & 63, w = tid >> 6;
  const int wm = (w >> 2) * 64, wn = (w & 3) * 64;
  const int lrow = lane & 15, kc = lane >> 4;
  int offA[4], offB[4];
#pragma unroll
  for (int i = 0; i < 4; i++) {
    int rA = wm + i * 16 + lrow;
    offA[i] = rA * 32 + (kc ^ ((rA >> 1) & 3)) * 8;
    int rB = wn + i * 16 + lrow;
    offB[i] = 4096 + rB * 32 + (kc ^ ((rB >> 1) & 3)) * 8;
  }

  f32x4 acc[4][4];
#pragma unroll
  for (int i = 0; i < 4; i++)
#pragma unroll
    for (int j = 0; j < 4; j++) acc[i][j] = f32x4{0.f, 0.f, 0.f, 0.f};

  const int nk = K >> 5;
  // prologue: stage K-steps 0 and 1
  {
    u16* b0 = lds;
    GLL(gA, b0 + dAo);
    GLL(gB0, b0 + dBo);
    GLL(gB1, b0 + dBo + 4096);
    u16* b1 = lds + 12288;
    GLL(gA + 32, b1 + dAo);
    GLL(gB0 + 32, b1 + dBo);
    GLL(gB1 + 32, b1 + dBo + 4096);
  }
  int cur = 0, stg = 2;
  for (int t = 0; t < nk; ++t) {
    // wait for K-step t's 3 loads; K-step t+1's 3 stay in flight
    asm volatile("s_waitcnt vmcnt(3)" ::: "memory");
    __builtin_amdgcn_s_barrier();
    u16* buf = lds + cur * 12288;
    bf16x8 af[4], bfv[4];
#pragma unroll
    for (int i = 0; i < 4; i++) af[i] = *(const bf16x8*)(buf + offA[i]);
#pragma unroll
    for (int i = 0; i < 4; i++) bfv[i] = *(const bf16x8*)(buf + offB[i]);
    // stage K-step t+2 (wrap: harmless re-stage into a dead buffer at the tail)
    int t2 = t + 2;
    if (t2 >= nk) t2 -= nk;
    {
      u16* sb = lds + stg * 12288;
      const int kk = t2 * 32;
      GLL(gA + kk, sb + dAo);
      GLL(gB0 + kk, sb + dBo);
      GLL(gB1 + kk, sb + dBo + 4096);
    }
    __builtin_amdgcn_s_barrier();
    __builtin_amdgcn_s_setprio(1);
#pragma unroll
    for (int mi = 0; mi < 4; mi++)
#pragma unroll
      for (int ni = 0; ni < 4; ni++)
        acc[mi][ni] = __builtin_amdgcn_mfma_f32_16x16x32_bf16(af[mi], bfv[ni],
                                                              acc[mi][ni], 0, 0, 0);
    __builtin_amdgcn_s_setprio(0);
    cur = (cur == 2) ? 0 : cur + 1;
    stg = (stg == 2) ? 0 : stg + 1;
  }
  // drain trailing wrap-stages before LDS dealloc at kernel end
  asm volatile("s_waitcnt vmcnt(0)" ::: "memory");

  // C/D layout: col = lane&15, row = (lane>>4)*4 + reg   [measured m89/m91]
  const int crow = row0 + wm + ((lane >> 4) << 2);
  const int ccol = nt * 256 + wn + (lane & 15);
#pragma unroll
  for (int mi = 0; mi < 4; mi++) {
#pragma unroll
    for (int ni = 0; ni < 4; ni++) {
#pragma unroll
      for (int r = 0; r < 4; r++) {
        int row = crow + mi * 16 + r;
        int col = ccol + ni * 16;
        float v = acc[mi][ni][r];
        if constexpr (CMODE == 0) {
          Cb[(long)row * ldc + col] = f2bf(v);
        } else {
          Cf[(long)row * ldc + col] = v;
        }
      }
    }
  }
}

// ---- fused [routed gu | shared gu]: 320 + 256 blocks, 512 threads ----
__global__ __launch_bounds__(512, 4) void gemm_gu_fused(
    const u16* __restrict__ xb, const u16* __restrict__ wguT,
    const u16* __restrict__ sgsuT, u16* __restrict__ gur, u16* __restrict__ gus,
    const int* __restrict__ offp, const int* __restrict__ perm,
    const u16* __restrict__ zrow) {
  __shared__ __align__(16) u16 lds2[36864];  // 72KB, 3 pipeline buffers
  int bid = blockIdx.x;
  if (bid < 320) {
    gemm_body2<0, true, true>(bid >> 3, bid & 7, lds2, xb, HDIM, wguT,
                              (long)2 * IDIM * HDIM, HDIM, gur, nullptr, 2 * IDIM,
                              offp, perm, zrow);
  } else {
    int b = bid - 320;
    gemm_body2<0, false, false>(b >> 4, b & 15, lds2, xb, HDIM, sgsuT, 0, HDIM, gus,
                                nullptr, 2 * ISDIM, nullptr, nullptr, nullptr);
  }
}

// ---- fused [shared down fp32 | routed down bf16 -> eo]: 128 + 320 blocks ----
__global__ __launch_bounds__(512, 4) void gemm_down_plain(
    const u16* __restrict__ gus, const u16* __restrict__ sdT,
    const u16* __restrict__ gur, const u16* __restrict__ wdT, float* __restrict__ out,
    u16* __restrict__ eo, const int* __restrict__ offp) {
  __shared__ __align__(16) u16 lds2[36864];
  int bid = blockIdx.x;
  if (bid < 128) {
    gemm_body2<1, false, false>(bid >> 3, bid & 7, lds2, gus, 2 * ISDIM, sdT, 0, ISDIM,
                                nullptr, out, HDIM, nullptr, nullptr, nullptr);
  } else {
    int b = bid - 128;
    gemm_body2<0, false, true>(b >> 3, b & 7, lds2, gur, 2 * IDIM, wdT,
                               (long)HDIM * IDIM, IDIM, eo, nullptr, HDIM, offp,
                               nullptr, nullptr);
  }
}

// ---- combine: out[t] += w0*eo[r0] + w1*eo[r1] ----
__global__ __launch_bounds__(256) void combine_kernel(float* __restrict__ out,
                                                      const u16* __restrict__ eo,
                                                      const int* __restrict__ tokrow,
                                                      const float* __restrict__ topw) {
  const int t = blockIdx.x, tid = threadIdx.x;
  const long o = (long)t * HDIM + tid * 8;
  const int r0 = tokrow[t * 2], r1 = tokrow[t * 2 + 1];
  const float w0 = topw[t * 2], w1 = topw[t * 2 + 1];
  float4 a = *(const float4*)(out + o);
  float4 b = *(const float4*)(out + o + 4);
  uint4 e0 = *(const uint4*)(eo + (long)r0 * HDIM + tid * 8);
  uint4 e1 = *(const uint4*)(eo + (long)r1 * HDIM + tid * 8);
  const u32* p0 = &e0.x;
  const u32* p1 = &e1.x;
  float r[8] = {a.x, a.y, a.z, a.w, b.x, b.y, b.z, b.w};
#pragma unroll
  for (int j = 0; j < 4; j++) {
    r[j * 2 + 0] += w0 * bf2f((u16)(p0[j] & 0xFFFF)) + w1 * bf2f((u16)(p1[j] & 0xFFFF));
    r[j * 2 + 1] += w0 * bf2f((u16)(p0[j] >> 16)) + w1 * bf2f((u16)(p1[j] >> 16));
  }
  float4 oa = {r[0], r[1], r[2], r[3]};
  float4 ob = {r[4], r[5], r[6], r[7]};
  *(float4*)(out + o) = oa;
  *(float4*)(out + o + 4) = ob;
}

// ======== legacy 128x128 body (kept for fallback path, unchanged) ========
template <int CMODE, bool PERMA, bool SEGB>
__device__ __forceinline__ void gemm_body(
    int mt, int nt, u16* ldsA, u16* ldsB, const u16* __restrict__ A, long lda,
    const u16* __restrict__ B, long ldbz, int K, u16* __restrict__ Cb,
    float* __restrict__ Cf, long ldc, const int* __restrict__ offp,
    const int* __restrict__ perm, const float* __restrict__ topw,
    const u16* __restrict__ zrow) {
  const int row0 = mt * 128;
  if constexpr (SEGB) {
    if (row0 >= offp[8]) return;
    int e = 0;
    while (offp[e + 1] <= row0) ++e;
    B += (long)e * ldbz;
  }
  const int tid = threadIdx.x;
  const u16* gA[4];
  const u16* gB[4];
  u16 *lA[4], *lB[4];
#pragma unroll
  for (int j = 0; j < 4; j++) {
    int c = tid + 256 * j;
    int r = c >> 3, s = c & 7;
    int gk = (s ^ (r & 7)) * 8;  // swizzled global chunk
    const u16* arow;
    if constexpr (PERMA) {
      int p = perm[row0 + r];
      arow = (p < 0) ? zrow : A + (long)(p >> 1) * lda;
    } else {
      arow = A + (long)(row0 + r) * lda;
    }
    gA[j] = arow + gk;
    gB[j] = B + (long)(nt * 128 + r) * K + gk;
    lA[j] = ldsA + c * 8;
    lB[j] = ldsB + c * 8;
  }
  const int lane = tid & 63, wave = tid >> 6;
  const int wm = (wave & 1) * 64, wn = (wave >> 1) * 64;
  const int lrow = lane & 15;
  const int kchunk = lane >> 4;  // 0..3
  const int rsw = lrow & 7;

  f32x4 acc[4][4];
#pragma unroll
  for (int i = 0; i < 4; i++)
#pragma unroll
    for (int j = 0; j < 4; j++) acc[i][j] = f32x4{0.f, 0.f, 0.f, 0.f};

  const int nk = K >> 6;
  for (int kt = 0; kt < nk; ++kt) {
    const int kk = kt * 64;
#pragma unroll
    for (int j = 0; j < 4; j++) {
      GLL(gA[j] + kk, lA[j]);
      GLL(gB[j] + kk, lB[j]);
    }
    __syncthreads();
#pragma unroll
    for (int half = 0; half < 2; half++) {
      const int slot = (kchunk + half * 4) ^ rsw;
      bf16x8 af[4], bfv[4];
#pragma unroll
      for (int mi = 0; mi < 4; mi++)
        af[mi] = *(const bf16x8*)(ldsA + (wm + lrow + mi * 16) * 64 + slot * 8);
#pragma unroll
      for (int ni = 0; ni < 4; ni++)
        bfv[ni] = *(const bf16x8*)(ldsB + (wn + lrow + ni * 16) * 64 + slot * 8);
#pragma unroll
      for (int mi = 0; mi < 4; mi++)
#pragma unroll
        for (int ni = 0; ni < 4; ni++)
          acc[mi][ni] = __builtin_amdgcn_mfma_f32_16x16x32_bf16(af[mi], bfv[ni],
                                                                acc[mi][ni], 0, 0, 0);
    }
    __syncthreads();
  }

  const int crow = row0 + wm + ((lane >> 4) << 2);
  const int ccol = nt * 128 + wn + (lane & 15);
#pragma unroll
  for (int mi = 0; mi < 4; mi++) {
#pragma unroll
    for (int ni = 0; ni < 4; ni++) {
#pragma unroll
      for (int r = 0; r < 4; r++) {
        int row = crow + mi * 16 + r;
        int col = ccol + ni * 16;
        float v = acc[mi][ni][r];
        if constexpr (CMODE == 0) {
          Cb[(long)row * ldc + col] = f2bf(v);
        } else if constexpr (CMODE == 1) {
          Cf[(long)row * ldc + col] = v;
        } else if constexpr (CMODE == 2) {
          int p = perm[row];
          if (p >= 0) atomicAdd(Cf + (long)(p >> 1) * ldc + col, topw[p] * v);
        } else {
          atomicAdd(Cf + (long)row * ldc + col, v);
        }
      }
    }
  }
}

// ---- fallback kernels (small ws): atomic design, unchanged ----
__global__ __launch_bounds__(256) void gemm_routed_gu(
    const u16* __restrict__ xb, const u16* __restrict__ wT, u16* __restrict__ Cb,
    const int* __restrict__ offp, const int* __restrict__ perm,
    const u16* __restrict__ zrow) {
  __shared__ __align__(16) u16 ldsA[8192], ldsB[8192];
  gemm_body<0, true, true>(blockIdx.y, blockIdx.x, ldsA, ldsB, xb, HDIM, wT,
                           (long)IDIM * HDIM, HDIM, Cb, nullptr, 2 * IDIM, offp, perm,
                           nullptr, zrow);
}
__global__ __launch_bounds__(256) void gemm_shared_gu(const u16* __restrict__ xb,
                                                      const u16* __restrict__ sgsuT,
                                                      u16* __restrict__ gus) {
  __shared__ __align__(16) u16 ldsA[8192], ldsB[8192];
  gemm_body<0, false, false>(blockIdx.y, blockIdx.x, ldsA, ldsB, xb, HDIM, sgsuT, 0, HDIM,
                             gus, nullptr, 2 * ISDIM, nullptr, nullptr, nullptr, nullptr);
}
__global__ __launch_bounds__(256) void gemm_down_atomic(
    const u16* __restrict__ gus, const u16* __restrict__ sdT,
    const u16* __restrict__ gur, const u16* __restrict__ wdT, float* __restrict__ out,
    const int* __restrict__ offp, const int* __restrict__ perm,
    const float* __restrict__ topw) {
  __shared__ __align__(16) u16 ldsA[8192], ldsB[8192];
  int bid = blockIdx.x;
  if (bid < 256) {
    gemm_body<3, false, false>(bid / 16, bid % 16, ldsA, ldsB, gus, 2 * ISDIM, sdT, 0,
                               ISDIM, nullptr, out, HDIM, nullptr, nullptr, nullptr,
                               nullptr);
  } else {
    int b = bid - 256;
    gemm_body<2, false, true>(b / 16, b % 16, ldsA, ldsB, gur, 2 * IDIM, wdT,
                              (long)HDIM * IDIM, IDIM, nullptr, out, HDIM, offp, perm,
                              topw, nullptr);
  }
}

extern "C" void kernel_launch(void* const* d_in, const int* in_sizes, int n_in,
                              void* d_out, int out_size, void* d_ws, size_t ws_size,
                              hipStream_t stream) {
  const float* x  = (const float*)d_in[0];
  const float* gw = (const float*)d_in[1];
  const float* wg = (const float*)d_in[2];
  const float* wu = (const float*)d_in[3];
  const float* wd = (const float*)d_in[4];
  const float* sg = (const float*)d_in[5];
  const float* su = (const float*)d_in[6];
  const float* sd = (const float*)d_in[7];
  float* out = (float*)d_out;

  char* ws = (char*)d_ws;
  size_t off = 0;
  auto alloc = [&](size_t b) {
    size_t o = off;
    off += (b + 255) & ~(size_t)255;
    return (void*)(ws + o);
  };
  u16*   xb     = (u16*)alloc((size_t)T_TOK * HDIM * 2);
  u16*   gur    = (u16*)alloc((size_t)MAXROWS * 2 * IDIM * 2);  // g|u, hr in cols 0..I
  u16*   gus    = (u16*)alloc((size_t)T_TOK * 2 * ISDIM * 2);   // gs|us, hs in cols 0..IS
  float* topw   = (float*)alloc((size_t)T_TOK * 2 * 4);
  int*   topi   = (int*)alloc((size_t)T_TOK * 2 * 4);
  int*   tokrow = (int*)alloc((size_t)T_TOK * 2 * 4);
  int*   perm   = (int*)alloc(8192 * 4);
  int*   meta   = (int*)alloc(64 * 4);
  u16*   zrow   = (u16*)alloc(4096);
  size_t base = off;

  const size_t SZ_WGUT  = (size_t)NEXP * 2 * IDIM * HDIM * 2;  // 64 MiB
  const size_t SZ_SGSUT = (size_t)2 * ISDIM * HDIM * 2;        // 16 MiB
  const size_t SZ_SDT   = (size_t)HDIM * ISDIM * 2;            // 8 MiB
  const size_t SZ_WDT   = (size_t)NEXP * HDIM * IDIM * 2;      // 32 MiB
  const bool fused = ws_size >= base + SZ_WGUT + SZ_SGSUT;

  init_kernel<<<32, 256, 0, stream>>>(perm, meta, (int*)zrow);
  gate_kernel<<<T_TOK, 256, 0, stream>>>(x, gw, xb, out, topw, topi, meta);
  scan_kernel<<<1, 64, 0, stream>>>(meta);
  assign_kernel<<<16, 256, 0, stream>>>(topi, meta, perm, tokrow);

  if (fused) {
    u16* wguT  = (u16*)(ws + base);
    u16* sgsuT = (u16*)(ws + base + SZ_WGUT);
    u16* sdT   = wguT;                              // reuse after gu gemm
    u16* wdT   = wguT + SZ_SDT / 2;                 // elements
    u16* eo    = wguT + (SZ_SDT + SZ_WDT) / 2;      // 20 MiB in free tail of region
    // wg (z<8) + wu (z>=8) in one launch
    tcast2_kernel<<<dim3(IDIM / 64, HDIM / 64, 2 * NEXP), 256, 0, stream>>>(
        wg, wu, wguT, HDIM, IDIM, (long)HDIM * IDIM, (long)2 * IDIM * HDIM,
        (long)IDIM * HDIM, NEXP);
    // sg (z=0) + su (z=1) in one launch
    tcast2_kernel<<<dim3(ISDIM / 64, HDIM / 64, 2), 256, 0, stream>>>(
        sg, su, sgsuT, HDIM, ISDIM, 0, 0, (long)ISDIM * HDIM, 1);
    gemm_gu_fused<<<576, 512, 0, stream>>>(xb, wguT, sgsuT, gur, gus, meta + 16, perm,
                                           zrow);
    silu2_kernel<<<(MAXROWS * IDIM / 8 + T_TOK * ISDIM / 8) / 256, 256, 0, stream>>>(
        gur, gus);
    tcast_kernel<<<dim3(HDIM / 64, ISDIM / 64, 1), 256, 0, stream>>>(sd, sdT, ISDIM,
                                                                     HDIM, 0, 0);
    tcast_kernel<<<dim3(HDIM / 64, IDIM / 64, NEXP), 256, 0, stream>>>(
        wd, wdT, IDIM, HDIM, (long)IDIM * HDIM, (long)HDIM * IDIM);
    gemm_down_plain<<<448, 512, 0, stream>>>(gus, sdT, gur, wdT, out, eo, meta + 16);
    combine_kernel<<<T_TOK, 256, 0, stream>>>(out, eo, tokrow, topw);
  } else {
    u16* wT    = (u16*)(ws + base);  // 40 MiB region, sequentially reused
    u16* sgsuT = wT;
    u16* sdT   = wT;
    u16* wdT   = wT + SZ_SDT / 2;
    tcast_kernel<<<dim3(IDIM / 64, HDIM / 64, NEXP), 256, 0, stream>>>(
        wg, wT, HDIM, IDIM, (long)HDIM * IDIM, (long)IDIM * HDIM);
    gemm_routed_gu<<<dim3(8, MAXROWS / 128), 256, 0, stream>>>(xb, wT, gur, meta + 16,
                                                               perm, zrow);
    tcast_kernel<<<dim3(IDIM / 64, HDIM / 64, NEXP), 256, 0, stream>>>(
        wu, wT, HDIM, IDIM, (long)HDIM * IDIM, (long)IDIM * HDIM);
    gemm_routed_gu<<<dim3(8, MAXROWS / 128), 256, 0, stream>>>(xb, wT, gur + IDIM,
                                                               meta + 16, perm, zrow);
    silu_kernel<128><<<(MAXROWS * IDIM / 8) / 256, 256, 0, stream>>>(gur);
    tcast_kernel<<<dim3(ISDIM / 64, HDIM / 64, 1), 256, 0, stream>>>(sg, sgsuT, HDIM,
                                                                     ISDIM, 0, 0);
    tcast_kernel<<<dim3(ISDIM / 64, HDIM / 64, 1), 256, 0, stream>>>(
        su, sgsuT + (size_t)ISDIM * HDIM, HDIM, ISDIM, 0, 0);
    gemm_shared_gu<<<dim3(32, 16), 256, 0, stream>>>(xb, sgsuT, gus);
    silu_kernel<256><<<(T_TOK * ISDIM / 8) / 256, 256, 0, stream>>>(gus);
    tcast_kernel<<<dim3(HDIM / 64, ISDIM / 64, 1), 256, 0, stream>>>(sd, sdT, ISDIM,
                                                                     HDIM, 0, 0);
    tcast_kernel<<<dim3(HDIM / 64, IDIM / 64, NEXP), 256, 0, stream>>>(
        wd, wdT, IDIM, HDIM, (long)IDIM * HDIM, (long)HDIM * IDIM);
    gemm_down_atomic<<<896, 256, 0, stream>>>(gus, sdT, gur, wdT, out, meta + 16, perm,
                                              topw);
  }
}